// Round 16
// baseline (455.319 us; speedup 1.0000x reference)
//
#include <hip/hip_runtime.h>
#include <hip/hip_fp16.h>

#define NNODES 100000
#define NEDGES 3200000
#define NFEATS 128
#define HID 64
#define NGRAPHS 64
#define NPB 128                              // nodes per bucket
#define NBUCK ((NNODES + NPB - 1) / NPB)     // 782
#define NBLKA 128                            // binning blocks
#define EPB (NEDGES / NBLKA)                 // 25000 edges per binning block
#define NF4 16                               // feats per feature-group slice
#define SLICE ((size_t)NNODES * NF4)         // halves per slice (3.2MB)

// ---------- CSR build ----------

__global__ __launch_bounds__(256) void k_hist(const int* __restrict__ dst, int* __restrict__ cntmat) {
    __shared__ int h[NBUCK];
    for (int j = threadIdx.x; j < NBUCK; j += 256) h[j] = 0;
    __syncthreads();
    int e0 = blockIdx.x * EPB;
    for (int i = threadIdx.x; i < EPB; i += 256) atomicAdd(&h[dst[e0 + i] >> 7], 1);
    __syncthreads();
    for (int j = threadIdx.x; j < NBUCK; j += 256) cntmat[blockIdx.x * NBUCK + j] = h[j];
}

// parallel column sums: tot[j] = sum_b cntmat[b][j]  (coalesced across threads)
__global__ __launch_bounds__(256) void k_offsA(const int* __restrict__ cntmat, int* __restrict__ tot) {
    int j = blockIdx.x * 256 + threadIdx.x;
    if (j >= NBUCK) return;
    int s = 0;
#pragma unroll 8
    for (int b = 0; b < NBLKA; b++) s += cntmat[b * NBUCK + j];
    tot[j] = s;
}

// one block: wave-scan totals -> bbase; init pooled/gcnt
__global__ __launch_bounds__(256) void k_offsB(const int* __restrict__ tot, int* __restrict__ bbase,
                                               float* pooled, float* gcnt) {
    int tid = threadIdx.x;
    if (tid < 64) {
        int run = 0;
        for (int c = 0; c < NBUCK; c += 64) {
            int j = c + tid;
            int own = (j < NBUCK) ? tot[j] : 0;
            int v = own;
            for (int off = 1; off < 64; off <<= 1) {
                int u = __shfl_up(v, off);
                if (tid >= off) v += u;
            }
            if (j < NBUCK) bbase[j] = run + v - own;
            run += __shfl(v, 63);
        }
        if (tid == 0) bbase[NBUCK] = NEDGES;
    }
    for (int i = tid; i < NGRAPHS * HID; i += 256) pooled[i] = 0.f;
    if (tid < NGRAPHS) gcnt[tid] = 0.f;
}

// parallel per-(block,bucket) offsets (coalesced reads+writes across threads)
__global__ __launch_bounds__(256) void k_offsC(const int* __restrict__ cntmat, const int* __restrict__ bbase,
                                               int* __restrict__ offmat) {
    int j = blockIdx.x * 256 + threadIdx.x;
    if (j >= NBUCK) return;
    int run = bbase[j];
    for (int b = 0; b < NBLKA; b++) { offmat[b * NBUCK + j] = run; run += cntmat[b * NBUCK + j]; }
}

// place edges into bucket-local regions: LDS cursors, 4B packed record s|dloc<<17
__global__ __launch_bounds__(256) void k_bin(const int* __restrict__ src, const int* __restrict__ dst,
                                             const int* __restrict__ offmat, int* __restrict__ ebin) {
    __shared__ int cur[NBUCK];
    int b = blockIdx.x;
    for (int j = threadIdx.x; j < NBUCK; j += 256) cur[j] = offmat[b * NBUCK + j];
    __syncthreads();
    int e0 = b * EPB;
    for (int i = threadIdx.x; i < EPB; i += 256) {
        int s = src[e0 + i], d = dst[e0 + i];
        int p = atomicAdd(&cur[d >> 7], 1);
        ebin[p] = s | ((d & (NPB - 1)) << 17);
    }
}

// per bucket: histogram + scan -> cnt/rowptr/dinv, then counting-sort src -> cols
__global__ __launch_bounds__(256) void k_csr(const int* __restrict__ ebin, const int* __restrict__ bbase,
                                             int* __restrict__ cnt, int* __restrict__ rowptr,
                                             float* __restrict__ dinv, int* __restrict__ cols) {
    __shared__ int h[NPB];
    __shared__ int sc[NPB];
    __shared__ int cur[NPB];
    int j = blockIdx.x;
    int tid = threadIdx.x;
    if (tid < NPB) h[tid] = 0;
    __syncthreads();
    int lo = bbase[j], hi = bbase[j + 1];
    for (int i = lo + tid; i < hi; i += 256) atomicAdd(&h[ebin[i] >> 17], 1);
    __syncthreads();
    if (tid < 64) {
        int run = 0;
        for (int c = 0; c < NPB; c += 64) {
            int own = h[c + tid];
            int v = own;
            for (int off = 1; off < 64; off <<= 1) {
                int u = __shfl_up(v, off);
                if (tid >= off) v += u;
            }
            sc[c + tid] = run + v - own;
            run += __shfl(v, 63);
        }
    }
    __syncthreads();
    int node = j * NPB + tid;
    if (tid < NPB) {
        cur[tid] = lo + sc[tid];
        if (node < NNODES) {
            int c = h[tid];
            cnt[node] = c;
            rowptr[node] = lo + sc[tid];
            dinv[node] = rsqrtf((float)(c + 1));   // +1 self loop, always > 0
        }
    }
    __syncthreads();
    for (int i = lo + tid; i < hi; i += 256) {
        int r = ebin[i];
        int p = atomicAdd(&cur[r >> 17], 1);
        cols[p] = r & 0x1FFFF;
    }
}

// ---------- epilogue helper: write 32 acc cols (x dinv) to 2 feature-slices ----------

__device__ __forceinline__ void store_t4(float* acc, float dv, int jhalf, int node, __half* t4) {
#pragma unroll
    for (int hh = 0; hh < 2; hh++) {
        int fg = jhalf * 2 + hh;
        __half* tp = t4 + (size_t)fg * SLICE + (size_t)node * NF4;
        union { __half2 h2[8]; float4 f[2]; } u;
#pragma unroll
        for (int q = 0; q < 8; q++)
            u.h2[q] = __floats2half2_rn(acc[hh * 16 + 2 * q] * dv, acc[hh * 16 + 2 * q + 1] * dv);
        *(float4*)tp = u.f[0];
        *(float4*)(tp + 8) = u.f[1];
    }
}

// ---------- layer-1 transform: fp32 x[N,128] -> t4 slices (fp16, x dinv) ----------

#define CHK 32
#define CHKP 33

__global__ __launch_bounds__(256) void k_mm128(const float* __restrict__ in, const float* __restrict__ W,
                                               const float* __restrict__ dinv, __half* __restrict__ t4) {
    __shared__ float xs[128 * CHKP];
    const int tid = threadIdx.x;
    const int lane = tid & 63;
    const int wid = tid >> 6;
    const int jhalf = __builtin_amdgcn_readfirstlane(wid & 1);
    const int nloc = (wid >> 1) * 64 + lane;
    const int node0 = blockIdx.x * 128;
    const int node = node0 + nloc;

    float acc[32];
#pragma unroll
    for (int j = 0; j < 32; j++) acc[j] = 0.f;

    const int c4 = tid & 7;
    const int r0 = tid >> 3;

    for (int ko = 0; ko < 128; ko += CHK) {
        __syncthreads();
#pragma unroll
        for (int s = 0; s < 4; s++) {
            int r = r0 + s * 32;
            int gn = node0 + r;
            float4 v = make_float4(0.f, 0.f, 0.f, 0.f);
            if (gn < NNODES) v = *(const float4*)&in[(size_t)gn * 128 + c4 * 4 + ko];
            float* dp = &xs[r * CHKP + c4 * 4];
            dp[0] = v.x; dp[1] = v.y; dp[2] = v.z; dp[3] = v.w;
        }
        __syncthreads();
        for (int kk = 0; kk < CHK; kk++) {
            float xk = xs[nloc * CHKP + kk];
            const float* Wr = &W[(size_t)(ko + kk) * 64 + jhalf * 32];
#pragma unroll
            for (int j = 0; j < 32; j++) acc[j] = fmaf(xk, Wr[j], acc[j]);
        }
    }

    if (node < NNODES) store_t4(acc, dinv[node], jhalf, node, t4);
}

// ---------- layer-2/3 transform: fp16 relu'd B[N,64] -> t4 slices ----------

__global__ __launch_bounds__(256) void k_mmh(const __half* __restrict__ in, const float* __restrict__ W,
                                             const float* __restrict__ dinv, __half* __restrict__ t4) {
    __shared__ float xs[128 * 65];
    const int tid = threadIdx.x;
    const int lane = tid & 63;
    const int wid = tid >> 6;
    const int jhalf = __builtin_amdgcn_readfirstlane(wid & 1);
    const int nloc = (wid >> 1) * 64 + lane;
    const int node0 = blockIdx.x * 128;
    const int node = node0 + nloc;

    const int c8 = tid & 7;     // 8 chunks of 8 halves per 64-half row
    const int r0 = tid >> 3;
#pragma unroll
    for (int s = 0; s < 4; s++) {
        int r = r0 + s * 32;
        int gn = node0 + r;
        float4 raw = make_float4(0.f, 0.f, 0.f, 0.f);
        if (gn < NNODES) raw = *(const float4*)&in[(size_t)gn * 64 + c8 * 8];
        const __half2* hp = (const __half2*)&raw;
        float* dp = &xs[r * 65 + c8 * 8];
#pragma unroll
        for (int q = 0; q < 4; q++) {
            float2 f = __half22float2(hp[q]);
            dp[2 * q] = f.x; dp[2 * q + 1] = f.y;
        }
    }
    __syncthreads();

    float acc[32];
#pragma unroll
    for (int j = 0; j < 32; j++) acc[j] = 0.f;
    for (int kk = 0; kk < 64; kk++) {
        float xk = xs[nloc * 65 + kk];
        const float* Wr = &W[(size_t)kk * 64 + jhalf * 32];
#pragma unroll
        for (int j = 0; j < 32; j++) acc[j] = fmaf(xk, Wr[j], acc[j]);
    }

    if (node < NNODES) store_t4(acc, dinv[node], jhalf, node, t4);
}

// ---------- aggregation: XCD-pinned slices + wave-per-4-nodes ----------
// Wave = 4 nodes (16-lane groups); group = 4 edge-slots x 4 feat-lanes (16 feats, 32B row).
// fg = (bid&7)>>1 pins each 3.2MB slice to an XCD pair -> L2-resident gathers.
// B = relu(bias + dinv[d]*(t'[d] + sum_e t'[src])), fp16.

__global__ __launch_bounds__(256) void k_agg(const __half* __restrict__ t4, const int* __restrict__ rowptr,
                                             const int* __restrict__ cnt, const int* __restrict__ cols,
                                             const float* __restrict__ dinv, const float* __restrict__ bias,
                                             __half* __restrict__ B) {
    int bid = blockIdx.x;
    int fg = (bid & 7) >> 1;                  // 0..3, pinned per XCD pair
    int ng = (bid >> 3) * 2 + (bid & 1);      // 0..6249
    int tid = threadIdx.x;
    int grp = tid >> 4;                        // node within block's 16
    int slot = (tid >> 2) & 3;                 // edge slot 0..3
    int f = tid & 3;                           // feat quad (4 halves = 8B)
    int w = ng * 16 + grp;                     // node; 6250*16 == 100000 exactly
    const __half* ts = t4 + (size_t)fg * SLICE;
    int start = rowptr[w];
    int n = cnt[w];
    float4 acc = make_float4(0.f, 0.f, 0.f, 0.f);
    int e = slot;
    // 4-deep unroll: 4 cols loads (quad-broadcast), 4 independent 8B gathers in flight
    for (; e + 12 < n; e += 16) {
        int s0 = cols[start + e];
        int s1 = cols[start + e + 4];
        int s2 = cols[start + e + 8];
        int s3 = cols[start + e + 12];
        float2 r0 = *(const float2*)&ts[(size_t)s0 * NF4 + f * 4];
        float2 r1 = *(const float2*)&ts[(size_t)s1 * NF4 + f * 4];
        float2 r2 = *(const float2*)&ts[(size_t)s2 * NF4 + f * 4];
        float2 r3 = *(const float2*)&ts[(size_t)s3 * NF4 + f * 4];
        const __half2* h0 = (const __half2*)&r0; const __half2* h1 = (const __half2*)&r1;
        const __half2* h2 = (const __half2*)&r2; const __half2* h3 = (const __half2*)&r3;
        float2 a;
        a = __half22float2(h0[0]); acc.x += a.x; acc.y += a.y;
        a = __half22float2(h0[1]); acc.z += a.x; acc.w += a.y;
        a = __half22float2(h1[0]); acc.x += a.x; acc.y += a.y;
        a = __half22float2(h1[1]); acc.z += a.x; acc.w += a.y;
        a = __half22float2(h2[0]); acc.x += a.x; acc.y += a.y;
        a = __half22float2(h2[1]); acc.z += a.x; acc.w += a.y;
        a = __half22float2(h3[0]); acc.x += a.x; acc.y += a.y;
        a = __half22float2(h3[1]); acc.z += a.x; acc.w += a.y;
    }
    for (; e < n; e += 4) {
        float2 raw = *(const float2*)&ts[(size_t)cols[start + e] * NF4 + f * 4];
        const __half2* hp = (const __half2*)&raw;
        float2 f0 = __half22float2(hp[0]);
        float2 f1 = __half22float2(hp[1]);
        acc.x += f0.x; acc.y += f0.y; acc.z += f1.x; acc.w += f1.y;
    }
    // reduce the 4 edge slots within each 16-lane group (xor lane bits 2,3)
    acc.x += __shfl_xor(acc.x, 4); acc.y += __shfl_xor(acc.y, 4);
    acc.z += __shfl_xor(acc.z, 4); acc.w += __shfl_xor(acc.w, 4);
    acc.x += __shfl_xor(acc.x, 8); acc.y += __shfl_xor(acc.y, 8);
    acc.z += __shfl_xor(acc.z, 8); acc.w += __shfl_xor(acc.w, 8);
    if (slot == 0) {
        // self-loop term + bias, relu, pack fp16
        float2 raw = *(const float2*)&ts[(size_t)w * NF4 + f * 4];
        const __half2* hp = (const __half2*)&raw;
        float2 f0 = __half22float2(hp[0]);
        float2 f1 = __half22float2(hp[1]);
        float dv = dinv[w];
        float4 b4 = *(const float4*)&bias[fg * NF4 + f * 4];
        float ox = fmaxf(fmaf(dv, f0.x + acc.x, b4.x), 0.f);
        float oy = fmaxf(fmaf(dv, f0.y + acc.y, b4.y), 0.f);
        float oz = fmaxf(fmaf(dv, f1.x + acc.z, b4.z), 0.f);
        float ow = fmaxf(fmaf(dv, f1.y + acc.w, b4.w), 0.f);
        union { __half2 h2[2]; float2 ff; } u;
        u.h2[0] = __floats2half2_rn(ox, oy);
        u.h2[1] = __floats2half2_rn(oz, ow);
        *(float2*)&B[(size_t)w * 64 + fg * NF4 + f * 4] = u.ff;
    }
}

// ---------- pooling (fp16 relu'd B) + head ----------

#define POOL_CHUNK 32
__global__ __launch_bounds__(256) void k_pool(const __half* __restrict__ h, const int* __restrict__ batch,
                                              float* pooled, float* gcnt) {
    int w = (blockIdx.x * 256 + threadIdx.x) >> 6;
    int lane = threadIdx.x & 63;
    int start = w * POOL_CHUNK;
    if (start >= NNODES) return;
    int end = min(start + POOL_CHUNK, NNODES);
    int g = batch[start];
    float acc = 0.f;
    float cn = 0.f;
    int i = start;
    for (; i + 4 <= end; i += 4) {
        int b0 = batch[i], b1 = batch[i + 1], b2 = batch[i + 2], b3 = batch[i + 3];
        float v0 = __half2float(h[(size_t)i * 64 + lane]);
        float v1 = __half2float(h[(size_t)(i + 1) * 64 + lane]);
        float v2 = __half2float(h[(size_t)(i + 2) * 64 + lane]);
        float v3 = __half2float(h[(size_t)(i + 3) * 64 + lane]);
        if (b0 != g) {
            atomicAdd(&pooled[g * 64 + lane], acc);
            if (lane == 0) atomicAdd(&gcnt[g], cn);
            g = b0; acc = 0.f; cn = 0.f;
        }
        acc += v0; cn += 1.f;
        if (b1 != g) {
            atomicAdd(&pooled[g * 64 + lane], acc);
            if (lane == 0) atomicAdd(&gcnt[g], cn);
            g = b1; acc = 0.f; cn = 0.f;
        }
        acc += v1; cn += 1.f;
        if (b2 != g) {
            atomicAdd(&pooled[g * 64 + lane], acc);
            if (lane == 0) atomicAdd(&gcnt[g], cn);
            g = b2; acc = 0.f; cn = 0.f;
        }
        acc += v2; cn += 1.f;
        if (b3 != g) {
            atomicAdd(&pooled[g * 64 + lane], acc);
            if (lane == 0) atomicAdd(&gcnt[g], cn);
            g = b3; acc = 0.f; cn = 0.f;
        }
        acc += v3; cn += 1.f;
    }
    for (; i < end; i++) {
        int gi = batch[i];
        if (gi != g) {
            atomicAdd(&pooled[g * 64 + lane], acc);
            if (lane == 0) atomicAdd(&gcnt[g], cn);
            g = gi; acc = 0.f; cn = 0.f;
        }
        acc += __half2float(h[(size_t)i * 64 + lane]);
        cn += 1.f;
    }
    atomicAdd(&pooled[g * 64 + lane], acc);
    if (lane == 0) atomicAdd(&gcnt[g], cn);
}

__global__ __launch_bounds__(256) void k_final(const float* __restrict__ pooled, const float* __restrict__ gcnt,
                                               const float* __restrict__ Wl, const float* __restrict__ bl,
                                               float* __restrict__ out) {
    int g = (blockIdx.x * 256 + threadIdx.x) >> 6;
    int lane = threadIdx.x & 63;
    if (g >= NGRAPHS) return;
    float c = fmaxf(gcnt[g], 1.f);
    float v = pooled[g * 64 + lane] / c * Wl[lane];
#pragma unroll
    for (int off = 32; off; off >>= 1) v += __shfl_down(v, off);
    if (lane == 0) out[g] = v + bl[0];
}

// ---------- launch ----------

extern "C" void kernel_launch(void* const* d_in, const int* in_sizes, int n_in,
                              void* d_out, int out_size, void* d_ws, size_t ws_size,
                              hipStream_t stream) {
    const float* x  = (const float*)d_in[0];
    const int* ei   = (const int*)d_in[1];
    const int* batch = (const int*)d_in[2];
    const float* W1 = (const float*)d_in[3];
    const float* b1 = (const float*)d_in[4];
    const float* W2 = (const float*)d_in[5];
    const float* b2 = (const float*)d_in[6];
    const float* W3 = (const float*)d_in[7];
    const float* b3 = (const float*)d_in[8];
    const float* Wl = (const float*)d_in[9];
    const float* bl = (const float*)d_in[10];
    const int* src = ei;
    const int* dst = ei + NEDGES;

    char* ws = (char*)d_ws;
    size_t off = 0;
    auto alloc = [&](size_t bytes) { void* p = ws + off; off += (bytes + 255) & ~size_t(255); return p; };
    __half* t4     = (__half*)alloc((size_t)NNODES * 64 * 2);   // 4 sliced fp16 t' buffers (12.8MB)
    __half* B      = (__half*)alloc((size_t)NNODES * 64 * 2);   // fp16 relu'd activations (12.8MB)
    int*    cols   = (int*)alloc((size_t)NEDGES * 4);           // CSR src indices (12.8MB)
    float*  dinv   = (float*)alloc((size_t)NNODES * 4);
    int*    cnt    = (int*)alloc((size_t)NNODES * 4);
    int*    rowptr = (int*)alloc((size_t)NNODES * 4);
    int*    cntmat = (int*)alloc((size_t)NBLKA * NBUCK * 4);
    int*    offmat = (int*)alloc((size_t)NBLKA * NBUCK * 4);
    int*    tot    = (int*)alloc(NBUCK * 4);
    int*    bbase  = (int*)alloc((NBUCK + 1) * 4);
    float*  pooled = (float*)alloc(NGRAPHS * 64 * 4);
    float*  gcnt   = (float*)alloc(NGRAPHS * 4);
    float*  out    = (float*)d_out;
    int*    ebin   = (int*)t4;   // 12.8MB staging aliases t4 (dead before layer-1 k_mm128)

    const int NB_MM = (NNODES + 127) / 128;
    const int NB_AG = (NNODES / 16 / 2) * 8;  // 3125*8 = 25000 blocks
    const int NB_PL = ((NNODES + POOL_CHUNK - 1) / POOL_CHUNK + 3) / 4;
    const int NB_J  = (NBUCK + 255) / 256;

    k_hist<<<NBLKA, 256, 0, stream>>>(dst, cntmat);
    k_offsA<<<NB_J, 256, 0, stream>>>(cntmat, tot);
    k_offsB<<<1, 256, 0, stream>>>(tot, bbase, pooled, gcnt);
    k_offsC<<<NB_J, 256, 0, stream>>>(cntmat, bbase, offmat);
    k_bin<<<NBLKA, 256, 0, stream>>>(src, dst, offmat, ebin);
    k_csr<<<NBUCK, 256, 0, stream>>>(ebin, bbase, cnt, rowptr, dinv, cols);

    // layer 1
    k_mm128<<<NB_MM, 256, 0, stream>>>(x, W1, dinv, t4);
    k_agg<<<NB_AG, 256, 0, stream>>>(t4, rowptr, cnt, cols, dinv, b1, B);
    // layer 2
    k_mmh<<<NB_MM, 256, 0, stream>>>(B, W2, dinv, t4);
    k_agg<<<NB_AG, 256, 0, stream>>>(t4, rowptr, cnt, cols, dinv, b2, B);
    // layer 3
    k_mmh<<<NB_MM, 256, 0, stream>>>(B, W3, dinv, t4);
    k_agg<<<NB_AG, 256, 0, stream>>>(t4, rowptr, cnt, cols, dinv, b3, B);

    k_pool<<<NB_PL, 256, 0, stream>>>(B, batch, pooled, gcnt);
    k_final<<<(NGRAPHS * 64 + 255) / 256, 256, 0, stream>>>(pooled, gcnt, Wl, bl, out);
}

// Round 17
// 380.998 us; speedup vs baseline: 1.1951x; 1.1951x over previous
//
#include <hip/hip_runtime.h>
#include <hip/hip_fp16.h>

#define NNODES 100000
#define NEDGES 3200000
#define NFEATS 128
#define HID 64
#define NGRAPHS 64
#define NPB 128                              // nodes per bucket
#define NBUCK ((NNODES + NPB - 1) / NPB)     // 782
#define NBLKA 128                            // binning blocks
#define EPB (NEDGES / NBLKA)                 // 25000 edges per binning block

// ---------- CSR build ----------

__global__ __launch_bounds__(256) void k_hist(const int* __restrict__ dst, int* __restrict__ cntmat) {
    __shared__ int h[NBUCK];
    for (int j = threadIdx.x; j < NBUCK; j += 256) h[j] = 0;
    __syncthreads();
    const int4* d4 = (const int4*)(dst + blockIdx.x * EPB);
    for (int i = threadIdx.x; i < EPB / 4; i += 256) {
        int4 v = d4[i];
        atomicAdd(&h[v.x >> 7], 1);
        atomicAdd(&h[v.y >> 7], 1);
        atomicAdd(&h[v.z >> 7], 1);
        atomicAdd(&h[v.w >> 7], 1);
    }
    __syncthreads();
    for (int j = threadIdx.x; j < NBUCK; j += 256) cntmat[blockIdx.x * NBUCK + j] = h[j];
}

// parallel column sums: tot[j] = sum_b cntmat[b][j]  (coalesced across threads)
__global__ __launch_bounds__(256) void k_offsA(const int* __restrict__ cntmat, int* __restrict__ tot) {
    int j = blockIdx.x * 256 + threadIdx.x;
    if (j >= NBUCK) return;
    int s = 0;
#pragma unroll 8
    for (int b = 0; b < NBLKA; b++) s += cntmat[b * NBUCK + j];
    tot[j] = s;
}

// one block: wave-scan totals -> bbase; init pooled/gcnt
__global__ __launch_bounds__(256) void k_offsB(const int* __restrict__ tot, int* __restrict__ bbase,
                                               float* pooled, float* gcnt) {
    int tid = threadIdx.x;
    if (tid < 64) {
        int run = 0;
        for (int c = 0; c < NBUCK; c += 64) {
            int j = c + tid;
            int own = (j < NBUCK) ? tot[j] : 0;
            int v = own;
            for (int off = 1; off < 64; off <<= 1) {
                int u = __shfl_up(v, off);
                if (tid >= off) v += u;
            }
            if (j < NBUCK) bbase[j] = run + v - own;
            run += __shfl(v, 63);
        }
        if (tid == 0) bbase[NBUCK] = NEDGES;
    }
    for (int i = tid; i < NGRAPHS * HID; i += 256) pooled[i] = 0.f;
    if (tid < NGRAPHS) gcnt[tid] = 0.f;
}

// parallel per-(block,bucket) offsets (coalesced reads+writes across threads)
__global__ __launch_bounds__(256) void k_offsC(const int* __restrict__ cntmat, const int* __restrict__ bbase,
                                               int* __restrict__ offmat) {
    int j = blockIdx.x * 256 + threadIdx.x;
    if (j >= NBUCK) return;
    int run = bbase[j];
    for (int b = 0; b < NBLKA; b++) { offmat[b * NBUCK + j] = run; run += cntmat[b * NBUCK + j]; }
}

// place edges into bucket-local regions: LDS cursors, 4B packed record s|dloc<<17
__global__ __launch_bounds__(256) void k_bin(const int* __restrict__ src, const int* __restrict__ dst,
                                             const int* __restrict__ offmat, int* __restrict__ ebin) {
    __shared__ int cur[NBUCK];
    int b = blockIdx.x;
    for (int j = threadIdx.x; j < NBUCK; j += 256) cur[j] = offmat[b * NBUCK + j];
    __syncthreads();
    const int4* s4 = (const int4*)(src + b * EPB);
    const int4* d4 = (const int4*)(dst + b * EPB);
    for (int i = threadIdx.x; i < EPB / 4; i += 256) {
        int4 sv = s4[i];
        int4 dv = d4[i];
        int p0 = atomicAdd(&cur[dv.x >> 7], 1);
        ebin[p0] = sv.x | ((dv.x & (NPB - 1)) << 17);
        int p1 = atomicAdd(&cur[dv.y >> 7], 1);
        ebin[p1] = sv.y | ((dv.y & (NPB - 1)) << 17);
        int p2 = atomicAdd(&cur[dv.z >> 7], 1);
        ebin[p2] = sv.z | ((dv.z & (NPB - 1)) << 17);
        int p3 = atomicAdd(&cur[dv.w >> 7], 1);
        ebin[p3] = sv.w | ((dv.w & (NPB - 1)) << 17);
    }
}

// per bucket: histogram + scan -> cnt/rowptr/dinv, then counting-sort src -> cols
__global__ __launch_bounds__(256) void k_csr(const int* __restrict__ ebin, const int* __restrict__ bbase,
                                             int* __restrict__ cnt, int* __restrict__ rowptr,
                                             float* __restrict__ dinv, int* __restrict__ cols) {
    __shared__ int h[NPB];
    __shared__ int sc[NPB];
    __shared__ int cur[NPB];
    int j = blockIdx.x;
    int tid = threadIdx.x;
    if (tid < NPB) h[tid] = 0;
    __syncthreads();
    int lo = bbase[j], hi = bbase[j + 1];
    for (int i = lo + tid; i < hi; i += 256) atomicAdd(&h[ebin[i] >> 17], 1);
    __syncthreads();
    if (tid < 64) {
        int run = 0;
        for (int c = 0; c < NPB; c += 64) {
            int own = h[c + tid];
            int v = own;
            for (int off = 1; off < 64; off <<= 1) {
                int u = __shfl_up(v, off);
                if (tid >= off) v += u;
            }
            sc[c + tid] = run + v - own;
            run += __shfl(v, 63);
        }
    }
    __syncthreads();
    int node = j * NPB + tid;
    if (tid < NPB) {
        cur[tid] = lo + sc[tid];
        if (node < NNODES) {
            int c = h[tid];
            cnt[node] = c;
            rowptr[node] = lo + sc[tid];
            dinv[node] = rsqrtf((float)(c + 1));   // +1 self loop, always > 0
        }
    }
    __syncthreads();
    for (int i = lo + tid; i < hi; i += 256) {
        int r = ebin[i];
        int p = atomicAdd(&cur[r >> 17], 1);
        cols[p] = r & 0x1FFFF;
    }
}

// ---------- layer-1 transform: fp32 x[N,128] -> t' = (x@W)*dinv, fp16 [node][64] ----------

#define CHK 32
#define CHKP 33

__global__ __launch_bounds__(256) void k_mm128(const float* __restrict__ in, const float* __restrict__ W,
                                               const float* __restrict__ dinv, __half* __restrict__ t) {
    __shared__ float xs[128 * CHKP];
    const int tid = threadIdx.x;
    const int lane = tid & 63;
    const int wid = tid >> 6;
    const int jhalf = __builtin_amdgcn_readfirstlane(wid & 1);
    const int nloc = (wid >> 1) * 64 + lane;
    const int node0 = blockIdx.x * 128;
    const int node = node0 + nloc;

    float acc[32];
#pragma unroll
    for (int j = 0; j < 32; j++) acc[j] = 0.f;

    const int c4 = tid & 7;
    const int r0 = tid >> 3;

    for (int ko = 0; ko < 128; ko += CHK) {
        __syncthreads();
#pragma unroll
        for (int s = 0; s < 4; s++) {
            int r = r0 + s * 32;
            int gn = node0 + r;
            float4 v = make_float4(0.f, 0.f, 0.f, 0.f);
            if (gn < NNODES) v = *(const float4*)&in[(size_t)gn * 128 + c4 * 4 + ko];
            float* dp = &xs[r * CHKP + c4 * 4];
            dp[0] = v.x; dp[1] = v.y; dp[2] = v.z; dp[3] = v.w;
        }
        __syncthreads();
        for (int kk = 0; kk < CHK; kk++) {
            float xk = xs[nloc * CHKP + kk];
            const float* Wr = &W[(size_t)(ko + kk) * 64 + jhalf * 32];
#pragma unroll
            for (int j = 0; j < 32; j++) acc[j] = fmaf(xk, Wr[j], acc[j]);
        }
    }

    if (node < NNODES) {
        float dv = dinv[node];
        __half* tp = &t[(size_t)node * 64 + jhalf * 32];
#pragma unroll
        for (int j4 = 0; j4 < 4; j4++) {
            union { __half2 h2[4]; float4 f; } u;
#pragma unroll
            for (int q = 0; q < 4; q++)
                u.h2[q] = __floats2half2_rn(acc[j4*8 + 2*q] * dv, acc[j4*8 + 2*q + 1] * dv);
            *(float4*)&tp[j4 * 8] = u.f;
        }
    }
}

// ---------- layer-2/3 transform: fp16 relu'd B[N,64] -> t' fp16 [node][64] ----------

__global__ __launch_bounds__(256) void k_mmh(const __half* __restrict__ in, const float* __restrict__ W,
                                             const float* __restrict__ dinv, __half* __restrict__ t) {
    __shared__ float xs[128 * 65];
    const int tid = threadIdx.x;
    const int lane = tid & 63;
    const int wid = tid >> 6;
    const int jhalf = __builtin_amdgcn_readfirstlane(wid & 1);
    const int nloc = (wid >> 1) * 64 + lane;
    const int node0 = blockIdx.x * 128;
    const int node = node0 + nloc;

    const int c8 = tid & 7;     // 8 chunks of 8 halves per 64-half row
    const int r0 = tid >> 3;
#pragma unroll
    for (int s = 0; s < 4; s++) {
        int r = r0 + s * 32;
        int gn = node0 + r;
        float4 raw = make_float4(0.f, 0.f, 0.f, 0.f);
        if (gn < NNODES) raw = *(const float4*)&in[(size_t)gn * 64 + c8 * 8];
        const __half2* hp = (const __half2*)&raw;
        float* dp = &xs[r * 65 + c8 * 8];
#pragma unroll
        for (int q = 0; q < 4; q++) {
            float2 f = __half22float2(hp[q]);
            dp[2 * q] = f.x; dp[2 * q + 1] = f.y;
        }
    }
    __syncthreads();

    float acc[32];
#pragma unroll
    for (int j = 0; j < 32; j++) acc[j] = 0.f;
    for (int kk = 0; kk < 64; kk++) {
        float xk = xs[nloc * 65 + kk];
        const float* Wr = &W[(size_t)kk * 64 + jhalf * 32];
#pragma unroll
        for (int j = 0; j < 32; j++) acc[j] = fmaf(xk, Wr[j], acc[j]);
    }

    if (node < NNODES) {
        float dv = dinv[node];
        __half* tp = &t[(size_t)node * 64 + jhalf * 32];
#pragma unroll
        for (int j4 = 0; j4 < 4; j4++) {
            union { __half2 h2[4]; float4 f; } u;
#pragma unroll
            for (int q = 0; q < 4; q++)
                u.h2[q] = __floats2half2_rn(acc[j4*8 + 2*q] * dv, acc[j4*8 + 2*q + 1] * dv);
            *(float4*)&tp[j4 * 8] = u.f;
        }
    }
}

// ---------- aggregation: wave per node, 8 edges in flight per lane-group ----------
// B = relu(bias + dinv[d]*(t'[d] + sum_e t'[src])), stored fp16.

__global__ __launch_bounds__(256) void k_agg(const __half* __restrict__ t, const int* __restrict__ rowptr,
                                             const int* __restrict__ cnt, const int* __restrict__ cols,
                                             const float* __restrict__ dinv, const float* __restrict__ bias,
                                             __half* __restrict__ B) {
    int w = (blockIdx.x * 256 + threadIdx.x) >> 6;   // node
    int lane = threadIdx.x & 63;
    if (w >= NNODES) return;
    int qg = lane >> 4;      // edge-slot group 0..3
    int ql = lane & 15;      // half4 slot within the 64-half row
    int start = rowptr[w];
    int n = cnt[w];
    float4 acc = make_float4(0.f, 0.f, 0.f, 0.f);
    int e = 0;
    // 8-deep: 8 cols loads, then 8 independent row gathers, then accumulate
    for (; e + 32 <= n; e += 32) {
        int s0 = cols[start + e + qg];
        int s1 = cols[start + e + 4 + qg];
        int s2 = cols[start + e + 8 + qg];
        int s3 = cols[start + e + 12 + qg];
        int s4 = cols[start + e + 16 + qg];
        int s5 = cols[start + e + 20 + qg];
        int s6 = cols[start + e + 24 + qg];
        int s7 = cols[start + e + 28 + qg];
        float2 r0 = *(const float2*)&t[(size_t)s0 * 64 + ql * 4];
        float2 r1 = *(const float2*)&t[(size_t)s1 * 64 + ql * 4];
        float2 r2 = *(const float2*)&t[(size_t)s2 * 64 + ql * 4];
        float2 r3 = *(const float2*)&t[(size_t)s3 * 64 + ql * 4];
        float2 r4 = *(const float2*)&t[(size_t)s4 * 64 + ql * 4];
        float2 r5 = *(const float2*)&t[(size_t)s5 * 64 + ql * 4];
        float2 r6 = *(const float2*)&t[(size_t)s6 * 64 + ql * 4];
        float2 r7 = *(const float2*)&t[(size_t)s7 * 64 + ql * 4];
        const __half2* h0 = (const __half2*)&r0; const __half2* h1 = (const __half2*)&r1;
        const __half2* h2 = (const __half2*)&r2; const __half2* h3 = (const __half2*)&r3;
        const __half2* h4 = (const __half2*)&r4; const __half2* h5 = (const __half2*)&r5;
        const __half2* h6 = (const __half2*)&r6; const __half2* h7 = (const __half2*)&r7;
        float2 a;
        a = __half22float2(h0[0]); acc.x += a.x; acc.y += a.y;
        a = __half22float2(h0[1]); acc.z += a.x; acc.w += a.y;
        a = __half22float2(h1[0]); acc.x += a.x; acc.y += a.y;
        a = __half22float2(h1[1]); acc.z += a.x; acc.w += a.y;
        a = __half22float2(h2[0]); acc.x += a.x; acc.y += a.y;
        a = __half22float2(h2[1]); acc.z += a.x; acc.w += a.y;
        a = __half22float2(h3[0]); acc.x += a.x; acc.y += a.y;
        a = __half22float2(h3[1]); acc.z += a.x; acc.w += a.y;
        a = __half22float2(h4[0]); acc.x += a.x; acc.y += a.y;
        a = __half22float2(h4[1]); acc.z += a.x; acc.w += a.y;
        a = __half22float2(h5[0]); acc.x += a.x; acc.y += a.y;
        a = __half22float2(h5[1]); acc.z += a.x; acc.w += a.y;
        a = __half22float2(h6[0]); acc.x += a.x; acc.y += a.y;
        a = __half22float2(h6[1]); acc.z += a.x; acc.w += a.y;
        a = __half22float2(h7[0]); acc.x += a.x; acc.y += a.y;
        a = __half22float2(h7[1]); acc.z += a.x; acc.w += a.y;
    }
    for (; e + 16 <= n; e += 16) {
        int s0 = cols[start + e + qg];
        int s1 = cols[start + e + 4 + qg];
        int s2 = cols[start + e + 8 + qg];
        int s3 = cols[start + e + 12 + qg];
        float2 r0 = *(const float2*)&t[(size_t)s0 * 64 + ql * 4];
        float2 r1 = *(const float2*)&t[(size_t)s1 * 64 + ql * 4];
        float2 r2 = *(const float2*)&t[(size_t)s2 * 64 + ql * 4];
        float2 r3 = *(const float2*)&t[(size_t)s3 * 64 + ql * 4];
        const __half2* h0 = (const __half2*)&r0; const __half2* h1 = (const __half2*)&r1;
        const __half2* h2 = (const __half2*)&r2; const __half2* h3 = (const __half2*)&r3;
        float2 a;
        a = __half22float2(h0[0]); acc.x += a.x; acc.y += a.y;
        a = __half22float2(h0[1]); acc.z += a.x; acc.w += a.y;
        a = __half22float2(h1[0]); acc.x += a.x; acc.y += a.y;
        a = __half22float2(h1[1]); acc.z += a.x; acc.w += a.y;
        a = __half22float2(h2[0]); acc.x += a.x; acc.y += a.y;
        a = __half22float2(h2[1]); acc.z += a.x; acc.w += a.y;
        a = __half22float2(h3[0]); acc.x += a.x; acc.y += a.y;
        a = __half22float2(h3[1]); acc.z += a.x; acc.w += a.y;
    }
    for (e += qg; e < n; e += 4) {
        float2 raw = *(const float2*)&t[(size_t)cols[start + e] * 64 + ql * 4];
        const __half2* hp = (const __half2*)&raw;
        float2 f0 = __half22float2(hp[0]);
        float2 f1 = __half22float2(hp[1]);
        acc.x += f0.x; acc.y += f0.y; acc.z += f1.x; acc.w += f1.y;
    }
    // reduce the 4 edge-slot groups (lanes l, l^16, l^32, l^48)
    acc.x += __shfl_xor(acc.x, 16); acc.y += __shfl_xor(acc.y, 16);
    acc.z += __shfl_xor(acc.z, 16); acc.w += __shfl_xor(acc.w, 16);
    acc.x += __shfl_xor(acc.x, 32); acc.y += __shfl_xor(acc.y, 32);
    acc.z += __shfl_xor(acc.z, 32); acc.w += __shfl_xor(acc.w, 32);
    if (qg == 0) {
        // self-loop term + bias, relu, pack fp16
        float2 raw = *(const float2*)&t[(size_t)w * 64 + ql * 4];
        const __half2* hp = (const __half2*)&raw;
        float2 f0 = __half22float2(hp[0]);
        float2 f1 = __half22float2(hp[1]);
        float dv = dinv[w];
        float4 b4 = *(const float4*)&bias[ql * 4];
        float ox = fmaxf(fmaf(dv, f0.x + acc.x, b4.x), 0.f);
        float oy = fmaxf(fmaf(dv, f0.y + acc.y, b4.y), 0.f);
        float oz = fmaxf(fmaf(dv, f1.x + acc.z, b4.z), 0.f);
        float ow = fmaxf(fmaf(dv, f1.y + acc.w, b4.w), 0.f);
        union { __half2 h2[2]; float2 ff; } u;
        u.h2[0] = __floats2half2_rn(ox, oy);
        u.h2[1] = __floats2half2_rn(oz, ow);
        *(float2*)&B[(size_t)w * 64 + ql * 4] = u.ff;
    }
}

// ---------- pooling (fp16 relu'd B) + head ----------

#define POOL_CHUNK 32
__global__ __launch_bounds__(256) void k_pool(const __half* __restrict__ h, const int* __restrict__ batch,
                                              float* pooled, float* gcnt) {
    int w = (blockIdx.x * 256 + threadIdx.x) >> 6;
    int lane = threadIdx.x & 63;
    int start = w * POOL_CHUNK;
    if (start >= NNODES) return;
    int end = min(start + POOL_CHUNK, NNODES);
    int g = batch[start];
    float acc = 0.f;
    float cn = 0.f;
    int i = start;
    for (; i + 4 <= end; i += 4) {
        int b0 = batch[i], b1 = batch[i + 1], b2 = batch[i + 2], b3 = batch[i + 3];
        float v0 = __half2float(h[(size_t)i * 64 + lane]);
        float v1 = __half2float(h[(size_t)(i + 1) * 64 + lane]);
        float v2 = __half2float(h[(size_t)(i + 2) * 64 + lane]);
        float v3 = __half2float(h[(size_t)(i + 3) * 64 + lane]);
        if (b0 != g) {
            atomicAdd(&pooled[g * 64 + lane], acc);
            if (lane == 0) atomicAdd(&gcnt[g], cn);
            g = b0; acc = 0.f; cn = 0.f;
        }
        acc += v0; cn += 1.f;
        if (b1 != g) {
            atomicAdd(&pooled[g * 64 + lane], acc);
            if (lane == 0) atomicAdd(&gcnt[g], cn);
            g = b1; acc = 0.f; cn = 0.f;
        }
        acc += v1; cn += 1.f;
        if (b2 != g) {
            atomicAdd(&pooled[g * 64 + lane], acc);
            if (lane == 0) atomicAdd(&gcnt[g], cn);
            g = b2; acc = 0.f; cn = 0.f;
        }
        acc += v2; cn += 1.f;
        if (b3 != g) {
            atomicAdd(&pooled[g * 64 + lane], acc);
            if (lane == 0) atomicAdd(&gcnt[g], cn);
            g = b3; acc = 0.f; cn = 0.f;
        }
        acc += v3; cn += 1.f;
    }
    for (; i < end; i++) {
        int gi = batch[i];
        if (gi != g) {
            atomicAdd(&pooled[g * 64 + lane], acc);
            if (lane == 0) atomicAdd(&gcnt[g], cn);
            g = gi; acc = 0.f; cn = 0.f;
        }
        acc += __half2float(h[(size_t)i * 64 + lane]);
        cn += 1.f;
    }
    atomicAdd(&pooled[g * 64 + lane], acc);
    if (lane == 0) atomicAdd(&gcnt[g], cn);
}

__global__ __launch_bounds__(256) void k_final(const float* __restrict__ pooled, const float* __restrict__ gcnt,
                                               const float* __restrict__ Wl, const float* __restrict__ bl,
                                               float* __restrict__ out) {
    int g = (blockIdx.x * 256 + threadIdx.x) >> 6;
    int lane = threadIdx.x & 63;
    if (g >= NGRAPHS) return;
    float c = fmaxf(gcnt[g], 1.f);
    float v = pooled[g * 64 + lane] / c * Wl[lane];
#pragma unroll
    for (int off = 32; off; off >>= 1) v += __shfl_down(v, off);
    if (lane == 0) out[g] = v + bl[0];
}

// ---------- launch ----------

extern "C" void kernel_launch(void* const* d_in, const int* in_sizes, int n_in,
                              void* d_out, int out_size, void* d_ws, size_t ws_size,
                              hipStream_t stream) {
    const float* x  = (const float*)d_in[0];
    const int* ei   = (const int*)d_in[1];
    const int* batch = (const int*)d_in[2];
    const float* W1 = (const float*)d_in[3];
    const float* b1 = (const float*)d_in[4];
    const float* W2 = (const float*)d_in[5];
    const float* b2 = (const float*)d_in[6];
    const float* W3 = (const float*)d_in[7];
    const float* b3 = (const float*)d_in[8];
    const float* Wl = (const float*)d_in[9];
    const float* bl = (const float*)d_in[10];
    const int* src = ei;
    const int* dst = ei + NEDGES;

    char* ws = (char*)d_ws;
    size_t off = 0;
    auto alloc = [&](size_t bytes) { void* p = ws + off; off += (bytes + 255) & ~size_t(255); return p; };
    __half* t      = (__half*)alloc((size_t)NNODES * 64 * 2);   // fp16 t' buffer (12.8MB)
    __half* B      = (__half*)alloc((size_t)NNODES * 64 * 2);   // fp16 relu'd activations (12.8MB)
    int*    cols   = (int*)alloc((size_t)NEDGES * 4);           // CSR src indices (12.8MB)
    float*  dinv   = (float*)alloc((size_t)NNODES * 4);
    int*    cnt    = (int*)alloc((size_t)NNODES * 4);
    int*    rowptr = (int*)alloc((size_t)NNODES * 4);
    int*    cntmat = (int*)alloc((size_t)NBLKA * NBUCK * 4);
    int*    offmat = (int*)alloc((size_t)NBLKA * NBUCK * 4);
    int*    tot    = (int*)alloc(NBUCK * 4);
    int*    bbase  = (int*)alloc((NBUCK + 1) * 4);
    float*  pooled = (float*)alloc(NGRAPHS * 64 * 4);
    float*  gcnt   = (float*)alloc(NGRAPHS * 4);
    float*  out    = (float*)d_out;
    int*    ebin   = (int*)t;   // 12.8MB staging aliases t (dead before layer-1 k_mm128)

    const int NB_MM = (NNODES + 127) / 128;
    const int NB_W  = ((size_t)NNODES * 64 + 255) / 256;
    const int NB_PL = ((NNODES + POOL_CHUNK - 1) / POOL_CHUNK + 3) / 4;
    const int NB_J  = (NBUCK + 255) / 256;

    k_hist<<<NBLKA, 256, 0, stream>>>(dst, cntmat);
    k_offsA<<<NB_J, 256, 0, stream>>>(cntmat, tot);
    k_offsB<<<1, 256, 0, stream>>>(tot, bbase, pooled, gcnt);
    k_offsC<<<NB_J, 256, 0, stream>>>(cntmat, bbase, offmat);
    k_bin<<<NBLKA, 256, 0, stream>>>(src, dst, offmat, ebin);
    k_csr<<<NBUCK, 256, 0, stream>>>(ebin, bbase, cnt, rowptr, dinv, cols);

    // layer 1
    k_mm128<<<NB_MM, 256, 0, stream>>>(x, W1, dinv, t);
    k_agg<<<NB_W, 256, 0, stream>>>(t, rowptr, cnt, cols, dinv, b1, B);
    // layer 2
    k_mmh<<<NB_MM, 256, 0, stream>>>(B, W2, dinv, t);
    k_agg<<<NB_W, 256, 0, stream>>>(t, rowptr, cnt, cols, dinv, b2, B);
    // layer 3
    k_mmh<<<NB_MM, 256, 0, stream>>>(B, W3, dinv, t);
    k_agg<<<NB_W, 256, 0, stream>>>(t, rowptr, cnt, cols, dinv, b3, B);

    k_pool<<<NB_PL, 256, 0, stream>>>(B, batch, pooled, gcnt);
    k_final<<<(NGRAPHS * 64 + 255) / 256, 256, 0, stream>>>(pooled, gcnt, Wl, bl, out);
}